// Round 7
// baseline (269.795 us; speedup 1.0000x reference)
//
#include <hip/hip_runtime.h>
#include <cfloat>

typedef __bf16 bf16x8 __attribute__((ext_vector_type(8)));
typedef unsigned short ushort8 __attribute__((ext_vector_type(8)));
typedef float f32x16 __attribute__((ext_vector_type(16)));

#define S_SLICES 8

// Order-preserving float <-> uint maps (total order matches float order).
static __device__ __forceinline__ unsigned f2key(float f) {
    unsigned b = __float_as_uint(f);
    return (b & 0x80000000u) ? ~b : (b ^ 0x80000000u);
}
static __device__ __forceinline__ float key2f(unsigned k) {
    unsigned b = (k & 0x80000000u) ? (k ^ 0x80000000u) : ~k;
    return __uint_as_float(b);
}
// fp32 -> bf16 bits, round-to-nearest-even
static __device__ __forceinline__ unsigned short f2bf(float x) {
    unsigned u = __float_as_uint(x);
    return (unsigned short)((u + 0x7FFFu + ((u >> 16) & 1u)) >> 16);
}
static __device__ __forceinline__ float bfbits2f(unsigned short h) {
    return __uint_as_float(((unsigned)h) << 16);
}

// Builds lane-order MFMA fragments (32x32x16 bf16) for both sides, K layout:
//  A k-vec: [-2hx,-2hy,-2hz, -2hx,-2hy,-2hz, -2lx,-2ly,-2lz, sA1,sA2,sA3, 1,1,1, 0]
//  B k-vec: [ hx,  hy,  hz,   lx,  ly,  lz,   hx,  hy,  hz,  1,1,1, sB1,sB2,sB3, 0]
//  => sum_k A*B = nrmA + nrmB - 2(hh + hl + lh) ~= d2  (err ~1e-4)
// Fragment storage: frag[(tile*64 + lane)*8 + j], lane = q*32 + (point&31), k = q*8+j.
// Pad points (beyond n/m) get nrm = 1e30 -> never win a min, own rows never read.
// Also inits rowkey/colkey to 0xFFFFFFFF (= +inf key) and zeroes hdr.
__global__ __launch_bounds__(256) void prep_kernel(
    const float* __restrict__ A, const float* __restrict__ B,
    ushort8* __restrict__ AF, ushort8* __restrict__ BF,
    unsigned* __restrict__ rowkey, unsigned* __restrict__ colkey,
    float* __restrict__ hdr, int n, int m, int RT, int CT)
{
    const int i = blockIdx.x * 256 + threadIdx.x;
    if (i < 8) hdr[i] = 0.f;
    if (i < RT * 32) rowkey[i] = 0xFFFFFFFFu;
    if (i < CT * 32) colkey[i] = 0xFFFFFFFFu;
    const unsigned short one = 0x3F80;

    if (i < RT * 32) {               // A side
        float x = 0.f, y = 0.f, z = 0.f, nrm = 1e30f;
        if (i < n) { x = A[3*i]; y = A[3*i+1]; z = A[3*i+2];
                     nrm = fmaf(x, x, fmaf(y, y, z * z)); }
        const unsigned short hx = f2bf(x), hy = f2bf(y), hz = f2bf(z);
        const unsigned short lx = f2bf(x - bfbits2f(hx)),
                             ly = f2bf(y - bfbits2f(hy)),
                             lz = f2bf(z - bfbits2f(hz));
        const unsigned short nhx = f2bf(-2.f * bfbits2f(hx)),
                             nhy = f2bf(-2.f * bfbits2f(hy)),
                             nhz = f2bf(-2.f * bfbits2f(hz));
        const unsigned short nlx = f2bf(-2.f * bfbits2f(lx)),
                             nly = f2bf(-2.f * bfbits2f(ly)),
                             nlz = f2bf(-2.f * bfbits2f(lz));
        float r = nrm;
        const unsigned short s1 = f2bf(r); r -= bfbits2f(s1);
        const unsigned short s2 = f2bf(r); r -= bfbits2f(s2);
        const unsigned short s3 = f2bf(r);
        ushort8 q0 = { nhx, nhy, nhz, nhx, nhy, nhz, nlx, nly };
        ushort8 q1 = { nlz, s1, s2, s3, one, one, one, 0 };
        const int rt = i >> 5, l5 = i & 31;
        AF[rt * 64 + l5]      = q0;
        AF[rt * 64 + 32 + l5] = q1;
    }
    if (i < CT * 32) {               // B side
        float x = 0.f, y = 0.f, z = 0.f, nrm = 1e30f;
        if (i < m) { x = B[3*i]; y = B[3*i+1]; z = B[3*i+2];
                     nrm = fmaf(x, x, fmaf(y, y, z * z)); }
        const unsigned short hx = f2bf(x), hy = f2bf(y), hz = f2bf(z);
        const unsigned short lx = f2bf(x - bfbits2f(hx)),
                             ly = f2bf(y - bfbits2f(hy)),
                             lz = f2bf(z - bfbits2f(hz));
        float r = nrm;
        const unsigned short s1 = f2bf(r); r -= bfbits2f(s1);
        const unsigned short s2 = f2bf(r); r -= bfbits2f(s2);
        const unsigned short s3 = f2bf(r);
        ushort8 q0 = { hx, hy, hz, lx, ly, lz, hx, hy };
        ushort8 q1 = { hz, one, one, one, s1, s2, s3, 0 };
        const int ct = i >> 5, l5 = i & 31;
        BF[ct * 64 + l5]      = q0;
        BF[ct * 64 + 32 + l5] = q1;
    }
}

// One wave per 32-row tile per column slice. Per col-tile: 1 MFMA produces the
// full 32x32 d2 tile (C map: col=lane&31, row=(reg&3)+8*(reg>>2)+4*(lane>>5)).
// Row mins accumulate in registers across the slice; col mins reduce in-tile
// (reg tree + xor32 shuffle) and combine globally via keyed atomicMin.
__global__ __launch_bounds__(256) void pairmin_kernel(
    const bf16x8* __restrict__ AF, const bf16x8* __restrict__ BF,
    unsigned* __restrict__ rowkey, unsigned* __restrict__ colkey,
    int RT, int CT)
{
    const int lane = threadIdx.x & 63;
    const int wave = threadIdx.x >> 6;
    const int rt = blockIdx.x * 4 + wave;
    if (rt >= RT) return;                      // wave-uniform

    const int ctPer = (CT + S_SLICES - 1) / S_SLICES;
    const int ctBeg = blockIdx.y * ctPer;
    const int ctEnd = min(ctBeg + ctPer, CT);

    const bf16x8 afrag = AF[rt * 64 + lane];   // loop-invariant A fragment

    float macc[16];
#pragma unroll
    for (int r = 0; r < 16; ++r) macc[r] = FLT_MAX;

    for (int ct = ctBeg; ct < ctEnd; ++ct) {
        const bf16x8 bfrag = BF[ct * 64 + lane];
        f32x16 C = {};
        C = __builtin_amdgcn_mfma_f32_32x32x16_bf16(afrag, bfrag, C, 0, 0, 0);

        // column-min over this tile's 32 rows
        float cm = fminf(C[0], C[1]);
#pragma unroll
        for (int r = 2; r < 16; ++r) cm = fminf(cm, C[r]);
        cm = fminf(cm, __shfl_xor(cm, 32, 64));          // other 16 rows
        atomicMin(&colkey[ct * 32 + (lane & 31)], f2key(cm));

        // row partial mins (per-reg, accumulated across the slice)
#pragma unroll
        for (int r = 0; r < 16; ++r) macc[r] = fminf(macc[r], C[r]);
    }

    // reduce row mins across the 32 lanes of each half-wave
#pragma unroll
    for (int r = 0; r < 16; ++r) {
        float v = macc[r];
        v = fminf(v, __shfl_xor(v, 1, 64));
        v = fminf(v, __shfl_xor(v, 2, 64));
        v = fminf(v, __shfl_xor(v, 4, 64));
        v = fminf(v, __shfl_xor(v, 8, 64));
        v = fminf(v, __shfl_xor(v, 16, 64));
        macc[r] = v;
    }
    if ((lane & 31) == 0) {
        const int q4 = (lane >> 5) * 4;
#pragma unroll
        for (int r = 0; r < 16; ++r) {
            const int row = (r & 3) + 8 * (r >> 2) + q4;
            atomicMin(&rowkey[rt * 32 + row], f2key(macc[r]));
        }
    }
}

// out layout: [loss+loss_seeds, mins_seeds(m), loss, loss_seeds]
__global__ __launch_bounds__(256) void finalize_kernel(
    const unsigned* __restrict__ rowkey, const unsigned* __restrict__ colkey,
    float* __restrict__ hdr, float* __restrict__ out, int n, int m)
{
    const int i = blockIdx.x * 256 + threadIdx.x;
    float sa = 0.f, sb = 0.f;
    if (i < n) sa = sqrtf(fmaxf(key2f(rowkey[i]), 0.f));
    if (i < m) {
        const float v = sqrtf(fmaxf(key2f(colkey[i]), 0.f));
        out[1 + i] = v;                  // mins_seeds
        sb = v;
    }

#pragma unroll
    for (int off = 32; off > 0; off >>= 1) {
        sa += __shfl_down(sa, off, 64);
        sb += __shfl_down(sb, off, 64);
    }
    __shared__ float reda[4], redb[4];
    const int wave = threadIdx.x >> 6;
    const int lane = threadIdx.x & 63;
    if (lane == 0) { reda[wave] = sa; redb[wave] = sb; }
    __syncthreads();

    if (threadIdx.x == 0) {
        const float ta = reda[0] + reda[1] + reda[2] + reda[3];
        const float tb = redb[0] + redb[1] + redb[2] + redb[3];
        atomicAdd(&hdr[0], ta);
        atomicAdd(&hdr[1], tb);
        __threadfence();
        const unsigned ticket = atomicAdd((unsigned*)&hdr[2], 1u);
        if (ticket == (unsigned)(gridDim.x - 1)) {
            const float fa = atomicAdd(&hdr[0], 0.f);
            const float fb = atomicAdd(&hdr[1], 0.f);
            const float loss = fa / (float)n;
            const float loss_seeds = fb / (float)m;
            out[0] = loss + loss_seeds;
            out[1 + m] = loss;
            out[2 + m] = loss_seeds;
        }
    }
}

extern "C" void kernel_launch(void* const* d_in, const int* in_sizes, int n_in,
                              void* d_out, int out_size, void* d_ws, size_t ws_size,
                              hipStream_t stream) {
    const int n = in_sizes[0] / 3;   // true_pos count
    const int m = in_sizes[1] / 3;   // pred_pos count
    const float* A = (const float*)d_in[0];
    const float* B = (const float*)d_in[1];
    float* out = (float*)d_out;

    const int RT = (n + 31) / 32, CT = (m + 31) / 32;
    char* p = (char*)d_ws;
    float*    hdr    = (float*)p;     p += 64;
    unsigned* rowkey = (unsigned*)p;  p += (size_t)RT * 32 * 4;
    unsigned* colkey = (unsigned*)p;  p += (size_t)CT * 32 * 4;
    ushort8*  AFw    = (ushort8*)p;   p += (size_t)RT * 64 * 16;
    ushort8*  BFw    = (ushort8*)p;

    const int maxPts = ((RT > CT) ? RT : CT) * 32;
    prep_kernel<<<(maxPts + 255) / 256, 256, 0, stream>>>(
        A, B, AFw, BFw, rowkey, colkey, hdr, n, m, RT, CT);

    dim3 grid((RT + 3) / 4, S_SLICES);
    pairmin_kernel<<<grid, 256, 0, stream>>>(
        (const bf16x8*)AFw, (const bf16x8*)BFw, rowkey, colkey, RT, CT);

    const int maxnm = (n > m) ? n : m;
    finalize_kernel<<<(maxnm + 255) / 256, 256, 0, stream>>>(
        rowkey, colkey, hdr, out, n, m);
}

// Round 8
// 105.545 us; speedup vs baseline: 2.5562x; 2.5562x over previous
//
#include <hip/hip_runtime.h>
#include <cfloat>

typedef __bf16 bf16x8 __attribute__((ext_vector_type(8)));
typedef unsigned short ushort8 __attribute__((ext_vector_type(8)));
typedef float f32x16 __attribute__((ext_vector_type(16)));

#define S_SLICES 8

// fp32 -> bf16 bits, round-to-nearest-even
static __device__ __forceinline__ unsigned short f2bf(float x) {
    unsigned u = __float_as_uint(x);
    return (unsigned short)((u + 0x7FFFu + ((u >> 16) & 1u)) >> 16);
}
static __device__ __forceinline__ float bfbits2f(unsigned short h) {
    return __uint_as_float(((unsigned)h) << 16);
}

// Per point, build TWO 16-element K-vectors (verified in round 7):
//  row vec: [-2hx,-2hy,-2hz, -2hx,-2hy,-2hz, -2lx,-2ly,-2lz, s1,s2,s3, 1,1,1, 0]
//  col vec: [ hx,  hy,  hz,   lx,  ly,  lz,   hx,  hy,  hz,  1,1,1, t1,t2,t3, 0]
//  => sum_k row[k]*col[k] = nrmRow + nrmCol - 2(hh+hl+lh) ~= d2 (err ~1e-4).
// Fragment storage (both operands share the map): frag[(tile*64)+q*32+l5],
// point = tile*32+l5, k = q*8+j. Pad points get nrm=1e30 -> never win a min.
__global__ __launch_bounds__(256) void prep_kernel(
    const float* __restrict__ A, const float* __restrict__ B,
    ushort8* __restrict__ RFA, ushort8* __restrict__ CFA,
    ushort8* __restrict__ RFB, ushort8* __restrict__ CFB,
    float* __restrict__ hdr, int n, int m, int RTn, int RTm)
{
    const int i = blockIdx.x * 256 + threadIdx.x;
    if (i < 8) hdr[i] = 0.f;
    const unsigned short one = 0x3F80;

#pragma unroll
    for (int side = 0; side < 2; ++side) {
        const int cntPts = side ? RTm * 32 : RTn * 32;
        if (i >= cntPts) continue;
        const float* P = side ? B : A;
        const int lim = side ? m : n;
        ushort8* RF = side ? RFB : RFA;
        ushort8* CF = side ? CFB : CFA;

        float x = 0.f, y = 0.f, z = 0.f, nrm = 1e30f;
        if (i < lim) { x = P[3*i]; y = P[3*i+1]; z = P[3*i+2];
                       nrm = fmaf(x, x, fmaf(y, y, z * z)); }
        const unsigned short hx = f2bf(x), hy = f2bf(y), hz = f2bf(z);
        const unsigned short lx = f2bf(x - bfbits2f(hx)),
                             ly = f2bf(y - bfbits2f(hy)),
                             lz = f2bf(z - bfbits2f(hz));
        const unsigned short nhx = f2bf(-2.f * bfbits2f(hx)),
                             nhy = f2bf(-2.f * bfbits2f(hy)),
                             nhz = f2bf(-2.f * bfbits2f(hz));
        const unsigned short nlx = f2bf(-2.f * bfbits2f(lx)),
                             nly = f2bf(-2.f * bfbits2f(ly)),
                             nlz = f2bf(-2.f * bfbits2f(lz));
        float r = nrm;
        const unsigned short s1 = f2bf(r); r -= bfbits2f(s1);
        const unsigned short s2 = f2bf(r); r -= bfbits2f(s2);
        const unsigned short s3 = f2bf(r);

        const int t = i >> 5, l5 = i & 31;
        ushort8 rq0 = { nhx, nhy, nhz, nhx, nhy, nhz, nlx, nly };
        ushort8 rq1 = { nlz, s1, s2, s3, one, one, one, 0 };
        RF[t * 64 + l5]      = rq0;
        RF[t * 64 + 32 + l5] = rq1;
        ushort8 cq0 = { hx, hy, hz, lx, ly, lz, hx, hy };
        ushort8 cq1 = { hz, one, one, one, s1, s2, s3, 0 };
        CF[t * 64 + l5]      = cq0;
        CF[t * 64 + 32 + l5] = cq1;
    }
}

// z=0: rows=A tiles vs cols=B tiles -> sbuf side 0 ("mins")
// z=1: rows=B tiles vs cols=A tiles -> sbuf side 1 ("mins_seeds")
// One wave per 32-row tile per column slice. Inner loop: prefetched bfrag
// load + 1 MFMA + 16 independent v_min (NO atomics, NO cross-lane — round 7's
// per-tile atomic chain was the 11K-cyc/tile disaster). Wave-level reduction
// + plain stores once at the end; finalize min-reduces the S_SLICES copies.
__global__ __launch_bounds__(256) void pairmin_kernel(
    const bf16x8* __restrict__ RFA, const bf16x8* __restrict__ CFA,
    const bf16x8* __restrict__ RFB, const bf16x8* __restrict__ CFB,
    float* __restrict__ sbuf, int RTn, int RTm)
{
    const int lane = threadIdx.x & 63;
    const int wave = threadIdx.x >> 6;

    const bf16x8* RF; const bf16x8* CF; float* sb; int rtCount, ctCount, stride;
    if (blockIdx.z == 0) { RF = RFA; CF = CFB; rtCount = RTn; ctCount = RTm;
                           sb = sbuf; stride = RTn * 32; }
    else                 { RF = RFB; CF = CFA; rtCount = RTm; ctCount = RTn;
                           sb = sbuf + (size_t)S_SLICES * RTn * 32;
                           stride = RTm * 32; }

    const int rt = blockIdx.x * 4 + wave;
    if (rt >= rtCount) return;                       // wave-uniform
    sb += (size_t)blockIdx.y * stride;

    const int ctPer = (ctCount + S_SLICES - 1) / S_SLICES;
    const int ctBeg = min(blockIdx.y * ctPer, ctCount);
    const int ctEnd = min(ctBeg + ctPer, ctCount);

    const bf16x8 afrag = RF[rt * 64 + lane];         // loop-invariant

    float macc[16];
#pragma unroll
    for (int r = 0; r < 16; ++r) macc[r] = FLT_MAX;

    if (ctBeg < ctEnd) {
        bf16x8 bcur = CF[ctBeg * 64 + lane];
        for (int ct = ctBeg; ct < ctEnd; ++ct) {
            const int ctn = (ct + 1 < ctEnd) ? ct + 1 : ct;   // safe prefetch
            const bf16x8 bnext = CF[ctn * 64 + lane];
            f32x16 C = {};
            C = __builtin_amdgcn_mfma_f32_32x32x16_bf16(afrag, bcur, C, 0, 0, 0);
#pragma unroll
            for (int r = 0; r < 16; ++r) macc[r] = fminf(macc[r], C[r]);
            bcur = bnext;
        }
    }

    // reduce row mins across the 32 cols held in each 32-lane half
#pragma unroll
    for (int r = 0; r < 16; ++r) {
        float v = macc[r];
        v = fminf(v, __shfl_xor(v, 1, 64));
        v = fminf(v, __shfl_xor(v, 2, 64));
        v = fminf(v, __shfl_xor(v, 4, 64));
        v = fminf(v, __shfl_xor(v, 8, 64));
        v = fminf(v, __shfl_xor(v, 16, 64));
        macc[r] = v;
    }
    if ((lane & 31) == 0) {
        const int q4 = (lane >> 5) * 4;              // C map: row=(r&3)+8*(r>>2)+4*q
        float* dst = sb + rt * 32;
#pragma unroll
        for (int r = 0; r < 16; ++r)
            dst[(r & 3) + 8 * (r >> 2) + q4] = macc[r];
    }
}

// out layout: [loss+loss_seeds, mins_seeds(m), loss, loss_seeds]
__global__ __launch_bounds__(256) void finalize_kernel(
    const float* __restrict__ sbuf, float* __restrict__ hdr,
    float* __restrict__ out, int n, int m, int RTn, int RTm)
{
    const int i = blockIdx.x * 256 + threadIdx.x;
    const int strideA = RTn * 32, strideB = RTm * 32;
    const float* sbB = sbuf + (size_t)S_SLICES * strideA;

    float sa = 0.f, sb_ = 0.f;
    if (i < n) {
        float s = FLT_MAX;
#pragma unroll
        for (int k = 0; k < S_SLICES; ++k) s = fminf(s, sbuf[(size_t)k * strideA + i]);
        sa = sqrtf(fmaxf(s, 0.f));
    }
    if (i < m) {
        float s = FLT_MAX;
#pragma unroll
        for (int k = 0; k < S_SLICES; ++k) s = fminf(s, sbB[(size_t)k * strideB + i]);
        const float v = sqrtf(fmaxf(s, 0.f));
        out[1 + i] = v;                  // mins_seeds
        sb_ = v;
    }

#pragma unroll
    for (int off = 32; off > 0; off >>= 1) {
        sa  += __shfl_down(sa,  off, 64);
        sb_ += __shfl_down(sb_, off, 64);
    }
    __shared__ float reda[4], redb[4];
    const int wave = threadIdx.x >> 6;
    const int lane = threadIdx.x & 63;
    if (lane == 0) { reda[wave] = sa; redb[wave] = sb_; }
    __syncthreads();

    if (threadIdx.x == 0) {
        const float ta = reda[0] + reda[1] + reda[2] + reda[3];
        const float tb = redb[0] + redb[1] + redb[2] + redb[3];
        atomicAdd(&hdr[0], ta);
        atomicAdd(&hdr[1], tb);
        __threadfence();
        const unsigned ticket = atomicAdd((unsigned*)&hdr[2], 1u);
        if (ticket == (unsigned)(gridDim.x - 1)) {
            const float fa = atomicAdd(&hdr[0], 0.f);
            const float fb = atomicAdd(&hdr[1], 0.f);
            const float loss = fa / (float)n;
            const float loss_seeds = fb / (float)m;
            out[0] = loss + loss_seeds;
            out[1 + m] = loss;
            out[2 + m] = loss_seeds;
        }
    }
}

extern "C" void kernel_launch(void* const* d_in, const int* in_sizes, int n_in,
                              void* d_out, int out_size, void* d_ws, size_t ws_size,
                              hipStream_t stream) {
    const int n = in_sizes[0] / 3;   // true_pos count
    const int m = in_sizes[1] / 3;   // pred_pos count
    const float* A = (const float*)d_in[0];
    const float* B = (const float*)d_in[1];
    float* out = (float*)d_out;

    const int RTn = (n + 31) / 32, RTm = (m + 31) / 32;
    char* p = (char*)d_ws;
    float*   hdr  = (float*)p;    p += 64;
    float*   sbuf = (float*)p;    p += (size_t)S_SLICES * (RTn + RTm) * 32 * 4;
    ushort8* RFA  = (ushort8*)p;  p += (size_t)RTn * 64 * 16;
    ushort8* CFA  = (ushort8*)p;  p += (size_t)RTn * 64 * 16;
    ushort8* RFB  = (ushort8*)p;  p += (size_t)RTm * 64 * 16;
    ushort8* CFB  = (ushort8*)p;

    const int maxPts = ((RTn > RTm) ? RTn : RTm) * 32;
    prep_kernel<<<(maxPts + 255) / 256, 256, 0, stream>>>(
        A, B, RFA, CFA, RFB, CFB, hdr, n, m, RTn, RTm);

    const int maxRT = (RTn > RTm) ? RTn : RTm;
    dim3 grid((maxRT + 3) / 4, S_SLICES, 2);
    pairmin_kernel<<<grid, 256, 0, stream>>>(
        (const bf16x8*)RFA, (const bf16x8*)CFA,
        (const bf16x8*)RFB, (const bf16x8*)CFB, sbuf, RTn, RTm);

    const int maxnm = (n > m) ? n : m;
    finalize_kernel<<<(maxnm + 255) / 256, 256, 0, stream>>>(
        sbuf, hdr, out, n, m, RTn, RTm);
}

// Round 9
// 80.843 us; speedup vs baseline: 3.3373x; 1.3055x over previous
//
#include <hip/hip_runtime.h>
#include <cfloat>

typedef __bf16 bf16x8 __attribute__((ext_vector_type(8)));
typedef unsigned short ushort8 __attribute__((ext_vector_type(8)));
typedef float f32x16 __attribute__((ext_vector_type(16)));

#define S_SLICES 8

// fp32 -> bf16 bits, round-to-nearest-even
static __device__ __forceinline__ unsigned short f2bf(float x) {
    unsigned u = __float_as_uint(x);
    return (unsigned short)((u + 0x7FFFu + ((u >> 16) & 1u)) >> 16);
}
static __device__ __forceinline__ float bfbits2f(unsigned short h) {
    return __uint_as_float(((unsigned)h) << 16);
}

// Per point, build TWO 16-element K-vectors (verified round 7/8):
//  row vec: [-2hx,-2hy,-2hz, -2hx,-2hy,-2hz, -2lx,-2ly,-2lz, s1,s2,s3, 1,1,1, 0]
//  col vec: [ hx,  hy,  hz,   lx,  ly,  lz,   hx,  hy,  hz,  1,1,1, t1,t2,t3, 0]
//  => sum_k row[k]*col[k] = nrmRow + nrmCol - 2(hh+hl+lh) ~= d2 (err ~1e-4).
// Fragment storage: frag[tile*64 + q*32 + l5], point = tile*32+l5, k = q*8+j.
// Pad points get nrm=1e30 -> never win a min.
__global__ __launch_bounds__(256) void prep_kernel(
    const float* __restrict__ A, const float* __restrict__ B,
    ushort8* __restrict__ RFA, ushort8* __restrict__ CFA,
    ushort8* __restrict__ RFB, ushort8* __restrict__ CFB,
    float* __restrict__ hdr, int n, int m, int RTn, int RTm)
{
    const int i = blockIdx.x * 256 + threadIdx.x;
    if (i < 8) hdr[i] = 0.f;
    const unsigned short one = 0x3F80;

#pragma unroll
    for (int side = 0; side < 2; ++side) {
        const int cntPts = side ? RTm * 32 : RTn * 32;
        if (i >= cntPts) continue;
        const float* P = side ? B : A;
        const int lim = side ? m : n;
        ushort8* RF = side ? RFB : RFA;
        ushort8* CF = side ? CFB : CFA;

        float x = 0.f, y = 0.f, z = 0.f, nrm = 1e30f;
        if (i < lim) { x = P[3*i]; y = P[3*i+1]; z = P[3*i+2];
                       nrm = fmaf(x, x, fmaf(y, y, z * z)); }
        const unsigned short hx = f2bf(x), hy = f2bf(y), hz = f2bf(z);
        const unsigned short lx = f2bf(x - bfbits2f(hx)),
                             ly = f2bf(y - bfbits2f(hy)),
                             lz = f2bf(z - bfbits2f(hz));
        const unsigned short nhx = f2bf(-2.f * bfbits2f(hx)),
                             nhy = f2bf(-2.f * bfbits2f(hy)),
                             nhz = f2bf(-2.f * bfbits2f(hz));
        const unsigned short nlx = f2bf(-2.f * bfbits2f(lx)),
                             nly = f2bf(-2.f * bfbits2f(ly)),
                             nlz = f2bf(-2.f * bfbits2f(lz));
        float r = nrm;
        const unsigned short s1 = f2bf(r); r -= bfbits2f(s1);
        const unsigned short s2 = f2bf(r); r -= bfbits2f(s2);
        const unsigned short s3 = f2bf(r);

        const int t = i >> 5, l5 = i & 31;
        ushort8 rq0 = { nhx, nhy, nhz, nhx, nhy, nhz, nlx, nly };
        ushort8 rq1 = { nlz, s1, s2, s3, one, one, one, 0 };
        RF[t * 64 + l5]      = rq0;
        RF[t * 64 + 32 + l5] = rq1;
        ushort8 cq0 = { hx, hy, hz, lx, ly, lz, hx, hy };
        ushort8 cq1 = { hz, one, one, one, s1, s2, s3, 0 };
        CF[t * 64 + l5]      = cq0;
        CF[t * 64 + 32 + l5] = cq1;
    }
}

// z=0: rows=A vs cols=B -> sbuf side 0 ("mins"); z=1: transposed ("mins_seeds").
// __launch_bounds__(256,4): 128-VGPR budget so the MFMA accumulator stays in
// VGPRs (round 8: default bounds -> 64-VGPR budget -> C in AGPRs -> 32
// accvgpr moves/tile = 3x VALU). Two C tiles in flight hide MFMA latency.
__global__ __launch_bounds__(256, 4) void pairmin_kernel(
    const bf16x8* __restrict__ RFA, const bf16x8* __restrict__ CFA,
    const bf16x8* __restrict__ RFB, const bf16x8* __restrict__ CFB,
    float* __restrict__ sbuf, int RTn, int RTm)
{
    const int lane = threadIdx.x & 63;
    const int wave = threadIdx.x >> 6;

    const bf16x8* RF; const bf16x8* CF; float* sb; int rtCount, ctCount, stride;
    if (blockIdx.z == 0) { RF = RFA; CF = CFB; rtCount = RTn; ctCount = RTm;
                           sb = sbuf; stride = RTn * 32; }
    else                 { RF = RFB; CF = CFA; rtCount = RTm; ctCount = RTn;
                           sb = sbuf + (size_t)S_SLICES * RTn * 32;
                           stride = RTm * 32; }

    const int rt = blockIdx.x * 4 + wave;
    if (rt >= rtCount) return;                       // wave-uniform
    sb += (size_t)blockIdx.y * stride;

    const int ctPer = (ctCount + S_SLICES - 1) / S_SLICES;
    const int ctBeg = min(blockIdx.y * ctPer, ctCount);
    const int ctEnd = min(ctBeg + ctPer, ctCount);

    const bf16x8 afrag = RF[rt * 64 + lane];         // loop-invariant
    const f32x16 zc = {};                            // hoisted zero C-operand

    float macc[16];
#pragma unroll
    for (int r = 0; r < 16; ++r) macc[r] = FLT_MAX;

    if (ctBeg < ctEnd) {
        int ct = ctBeg;
        bf16x8 b0 = CF[ct * 64 + lane];
        f32x16 C0 = __builtin_amdgcn_mfma_f32_32x32x16_bf16(afrag, b0, zc, 0, 0, 0);
        ++ct;
        for (; ct + 1 < ctEnd; ct += 2) {
            const bf16x8 b1 = CF[ct * 64 + lane];
            const f32x16 C1 =
                __builtin_amdgcn_mfma_f32_32x32x16_bf16(afrag, b1, zc, 0, 0, 0);
#pragma unroll
            for (int r = 0; r < 16; ++r) macc[r] = fminf(macc[r], C0[r]);
            const bf16x8 b2 = CF[(ct + 1) * 64 + lane];
            C0 = __builtin_amdgcn_mfma_f32_32x32x16_bf16(afrag, b2, zc, 0, 0, 0);
#pragma unroll
            for (int r = 0; r < 16; ++r) macc[r] = fminf(macc[r], C1[r]);
        }
        if (ct < ctEnd) {
            const bf16x8 b1 = CF[ct * 64 + lane];
            const f32x16 C1 =
                __builtin_amdgcn_mfma_f32_32x32x16_bf16(afrag, b1, zc, 0, 0, 0);
#pragma unroll
            for (int r = 0; r < 16; ++r) macc[r] = fminf(macc[r], C0[r]);
#pragma unroll
            for (int r = 0; r < 16; ++r) macc[r] = fminf(macc[r], C1[r]);
        } else {
#pragma unroll
            for (int r = 0; r < 16; ++r) macc[r] = fminf(macc[r], C0[r]);
        }
    }

    // reduce row mins across the 32 cols held in each 32-lane half
#pragma unroll
    for (int r = 0; r < 16; ++r) {
        float v = macc[r];
        v = fminf(v, __shfl_xor(v, 1, 64));
        v = fminf(v, __shfl_xor(v, 2, 64));
        v = fminf(v, __shfl_xor(v, 4, 64));
        v = fminf(v, __shfl_xor(v, 8, 64));
        v = fminf(v, __shfl_xor(v, 16, 64));
        macc[r] = v;
    }
    if ((lane & 31) == 0) {
        const int q4 = (lane >> 5) * 4;              // C map: row=(r&3)+8*(r>>2)+4*q
        float* dst = sb + rt * 32;
#pragma unroll
        for (int r = 0; r < 16; ++r)
            dst[(r & 3) + 8 * (r >> 2) + q4] = macc[r];
    }
}

// out layout: [loss+loss_seeds, mins_seeds(m), loss, loss_seeds]
__global__ __launch_bounds__(256) void finalize_kernel(
    const float* __restrict__ sbuf, float* __restrict__ hdr,
    float* __restrict__ out, int n, int m, int RTn, int RTm)
{
    const int i = blockIdx.x * 256 + threadIdx.x;
    const int strideA = RTn * 32, strideB = RTm * 32;
    const float* sbB = sbuf + (size_t)S_SLICES * strideA;

    float sa = 0.f, sb_ = 0.f;
    if (i < n) {
        float s = FLT_MAX;
#pragma unroll
        for (int k = 0; k < S_SLICES; ++k) s = fminf(s, sbuf[(size_t)k * strideA + i]);
        sa = sqrtf(fmaxf(s, 0.f));
    }
    if (i < m) {
        float s = FLT_MAX;
#pragma unroll
        for (int k = 0; k < S_SLICES; ++k) s = fminf(s, sbB[(size_t)k * strideB + i]);
        const float v = sqrtf(fmaxf(s, 0.f));
        out[1 + i] = v;                  // mins_seeds
        sb_ = v;
    }

#pragma unroll
    for (int off = 32; off > 0; off >>= 1) {
        sa  += __shfl_down(sa,  off, 64);
        sb_ += __shfl_down(sb_, off, 64);
    }
    __shared__ float reda[4], redb[4];
    const int wave = threadIdx.x >> 6;
    const int lane = threadIdx.x & 63;
    if (lane == 0) { reda[wave] = sa; redb[wave] = sb_; }
    __syncthreads();

    if (threadIdx.x == 0) {
        const float ta = reda[0] + reda[1] + reda[2] + reda[3];
        const float tb = redb[0] + redb[1] + redb[2] + redb[3];
        atomicAdd(&hdr[0], ta);
        atomicAdd(&hdr[1], tb);
        __threadfence();
        const unsigned ticket = atomicAdd((unsigned*)&hdr[2], 1u);
        if (ticket == (unsigned)(gridDim.x - 1)) {
            const float fa = atomicAdd(&hdr[0], 0.f);
            const float fb = atomicAdd(&hdr[1], 0.f);
            const float loss = fa / (float)n;
            const float loss_seeds = fb / (float)m;
            out[0] = loss + loss_seeds;
            out[1 + m] = loss;
            out[2 + m] = loss_seeds;
        }
    }
}

extern "C" void kernel_launch(void* const* d_in, const int* in_sizes, int n_in,
                              void* d_out, int out_size, void* d_ws, size_t ws_size,
                              hipStream_t stream) {
    const int n = in_sizes[0] / 3;   // true_pos count
    const int m = in_sizes[1] / 3;   // pred_pos count
    const float* A = (const float*)d_in[0];
    const float* B = (const float*)d_in[1];
    float* out = (float*)d_out;

    const int RTn = (n + 31) / 32, RTm = (m + 31) / 32;
    char* p = (char*)d_ws;
    float*   hdr  = (float*)p;    p += 64;
    float*   sbuf = (float*)p;    p += (size_t)S_SLICES * (RTn + RTm) * 32 * 4;
    ushort8* RFA  = (ushort8*)p;  p += (size_t)RTn * 64 * 16;
    ushort8* CFA  = (ushort8*)p;  p += (size_t)RTn * 64 * 16;
    ushort8* RFB  = (ushort8*)p;  p += (size_t)RTm * 64 * 16;
    ushort8* CFB  = (ushort8*)p;

    const int maxPts = ((RTn > RTm) ? RTn : RTm) * 32;
    prep_kernel<<<(maxPts + 255) / 256, 256, 0, stream>>>(
        A, B, RFA, CFA, RFB, CFB, hdr, n, m, RTn, RTm);

    const int maxRT = (RTn > RTm) ? RTn : RTm;
    dim3 grid((maxRT + 3) / 4, S_SLICES, 2);
    pairmin_kernel<<<grid, 256, 0, stream>>>(
        (const bf16x8*)RFA, (const bf16x8*)CFA,
        (const bf16x8*)RFB, (const bf16x8*)CFB, sbuf, RTn, RTm);

    const int maxnm = (n > m) ? n : m;
    finalize_kernel<<<(maxnm + 255) / 256, 256, 0, stream>>>(
        sbuf, hdr, out, n, m, RTn, RTm);
}